// Round 11
// baseline (62.197 us; speedup 1.0000x reference)
//
#include <hip/hip_runtime.h>

typedef unsigned short u16;
typedef __attribute__((ext_vector_type(8))) __bf16 bf16x8;
typedef __attribute__((ext_vector_type(4))) float f32x4;

#define GLOAD_LDS16(g, l)                                                                     \
  __builtin_amdgcn_global_load_lds((const __attribute__((address_space(1))) unsigned int*)(g), \
                                   (__attribute__((address_space(3))) unsigned int*)(l), 16, 0, 0)

static __device__ __forceinline__ u16 f2bf(float f) {
  unsigned int u = __float_as_uint(f);
  u += 0x7fffu + ((u >> 16) & 1u);   // round-to-nearest-even
  return (u16)(u >> 16);
}

// Problem constants
#define BATCH 32
#define NN 1024   // transform length
#define MM 512    // columns
#define KH 512    // folded K (p axis)

// Dual-bijective chunk swizzle (R8/R10-verified, 0 conflicts): bijective on
// row-step-1 (frag reads, 2 lanes/chunk per 16-lane beat) and row-step-2
// (X transpose writes, 2 lanes/chunk per beat). 2-way = free (m136).
static __device__ __forceinline__ int swz(int r) { return ((r >> 1) ^ ((r & 1) << 2)) & 7; }

// ---- kernel 1: pre-swizzled E|O matrix, laid out per (jh-tile, step) ----
// G[jt(8)][s(16)][jl(64)][64 u16]. Row (jt,s,jl): physical chunk cp holds data
// chunk dc = cp ^ swz(jl):
//   dc<4 : E part, p = s*32 + dc*8 + sub      -> M[j][2p]
//   dc>=4: O part, p = s*32 + (dc-4)*8 + sub  -> M[j][2p+1],  j = jt*64+jl
__global__ void fill_g(u16* __restrict__ G) {
  int idx = blockIdx.x * 256 + threadIdx.x;  // 8*16*64*64 = 524288
  int jt  = idx >> 16;
  int s   = (idx >> 12) & 15;
  int jl  = (idx >> 6) & 63;
  int r64 = idx & 63;
  int cp = r64 >> 3, sub = r64 & 7;
  int dc = cp ^ swz(jl);
  int j = jt * 64 + jl;
  int k;
  if (dc < 4) k = 2 * (s * 32 + dc * 8 + sub);
  else        k = 2 * (s * 32 + (dc - 4) * 8 + sub) + 1;
  float v;
  if (k == 0) {
    v = 0.03125f;  // 1/sqrt(1024)
  } else {
    int ph = (k * (2 * j + 1)) & 4095;
    v = 0.04419417382415922f * cosf((float)ph * 1.5339807878856412e-3f);
  }
  G[idx] = f2bf(v);
}

// ---- kernel 2: barrier-free single-wave fused folded GEMM ----
// Block = 1 wave, output 64jh x 32c (plus mirror rows). Grid 4096 -> 8 resident
// waves/CU (LDS 20480 B x 8 = 160 KiB), each free-running: NO __syncthreads.
// Per step s (32 p / 64 k), all sync = per-wave waitcnt:
//   top: vmcnt(0) [A(s),X(s) issued a FULL STEP ago -> latency amortized]
//        + lgkmcnt(0) [prev frag reads retired -> sX reusable]
//   WRITE_X(s): cvt + 4 swizzled ds_write_b128 (transpose)
//   issue A(s+1): 8 gload_lds (contiguous 1KB source each); X(s+1): 16 float2
//   lgkmcnt(0) [X writes visible to all lanes]; 12 ds_read frags; 16 MFMA.
// Independent waves at different phases cover each other's stalls (m114).
__global__ __launch_bounds__(64, 2) void gemm_idct(const u16* __restrict__ G,
                                                   const float* __restrict__ X,
                                                   float* __restrict__ C) {
  __shared__ __align__(16) u16 sA[2][64 * 64];  // 16 KiB: E|O interleaved, dbuf
  __shared__ __align__(16) u16 sX[32 * 64];     // 4 KiB: Xe|Xo interleaved
  // --- decode: 8 jt-sharers of each (ct,b) X-panel land on one XCD ---
  const int wg    = blockIdx.x;
  const int xcd   = wg & 7;
  const int local = wg >> 3;                  // 0..511
  const int jt    = local & 7;                // jh tile (64 rows)
  const int panel = xcd * 64 + (local >> 3);  // 0..511
  const int ct    = panel & 15;               // c tile (32 cols)
  const int b     = panel >> 4;               // batch

  const int l   = threadIdx.x;  // 0..63
  const int llo = l & 15, lhi = l >> 4;

  // --- A staging: per step 8 calls x 1KB contiguous; dest linear l*16B ---
  const u16* gA = G + (size_t)jt * 65536 + l * 8;
#define ISSUE_A(s)                                                            \
  do {                                                                        \
    u16* dst = &sA[(s) & 1][0];                                               \
    _Pragma("unroll") for (int cl = 0; cl < 8; ++cl)                          \
      GLOAD_LDS16(gA + (s) * 4096 + cl * 512, dst + cl * 512 + l * 8);        \
  } while (0)

  // --- X: lane owns c-pair {2*llo, 2*llo+1}, k in [lhi*16, lhi*16+16) ---
  const float* gX = X + ((size_t)b * NN + lhi * 16) * MM + ct * 32 + 2 * llo;

#define LOAD_X(s, XR)                                                         \
  do {                                                                        \
    const float* p = gX + (size_t)(s) * 64 * MM;                              \
    _Pragma("unroll") for (int i = 0; i < 16; ++i)                            \
      XR[i] = *(const float2*)(p + (size_t)i * MM);                           \
  } while (0)

  // p-local = lhi*8..+8 (contiguous): E chunk dc=lhi, O chunk dc=4+lhi
#define WRITE_X(XR)                                                           \
  do {                                                                        \
    _Pragma("unroll") for (int cc = 0; cc < 2; ++cc) {                        \
      const int row = 2 * llo + cc;                                           \
      const int f = swz(row);                                                 \
      bf16x8 e, o;                                                            \
      _Pragma("unroll") for (int m = 0; m < 8; ++m) {                         \
        e[m] = (__bf16)(cc ? XR[2 * m].y : XR[2 * m].x);                      \
        o[m] = (__bf16)(cc ? XR[2 * m + 1].y : XR[2 * m + 1].x);              \
      }                                                                       \
      *(bf16x8*)&sX[row * 64 + ((lhi ^ f) << 3)] = e;                         \
      *(bf16x8*)&sX[row * 64 + (((4 + lhi) ^ f) << 3)] = o;                   \
    }                                                                         \
  } while (0)

  f32x4 accE[4][2] = {};
  f32x4 accO[4][2] = {};
  float2 xrA[16], xrB[16];

#define STEP(s, XRC, XRN)                                                     \
  do {                                                                        \
    asm volatile("s_waitcnt vmcnt(0) lgkmcnt(0)" ::: "memory");               \
    __builtin_amdgcn_sched_barrier(0);                                        \
    WRITE_X(XRC);                                                             \
    if ((s) < 15) {                                                           \
      ISSUE_A((s) + 1);                                                       \
      LOAD_X((s) + 1, XRN);                                                   \
    }                                                                         \
    asm volatile("s_waitcnt lgkmcnt(0)" ::: "memory");                        \
    __builtin_amdgcn_sched_barrier(0);                                        \
    const u16* lA = &sA[(s) & 1][0];                                          \
    bf16x8 fe[4], fo[4], fxe[2], fxo[2];                                      \
    _Pragma("unroll") for (int mi = 0; mi < 4; ++mi) {                        \
      const int ra = mi * 16 + llo;                                           \
      const int fa = swz(ra);                                                 \
      fe[mi] = *(const bf16x8*)&lA[ra * 64 + ((lhi ^ fa) << 3)];              \
      fo[mi] = *(const bf16x8*)&lA[ra * 64 + (((4 + lhi) ^ fa) << 3)];        \
    }                                                                         \
    _Pragma("unroll") for (int ni = 0; ni < 2; ++ni) {                        \
      const int rb = ni * 16 + llo;                                           \
      const int fb = swz(rb);                                                 \
      fxe[ni] = *(const bf16x8*)&sX[rb * 64 + ((lhi ^ fb) << 3)];             \
      fxo[ni] = *(const bf16x8*)&sX[rb * 64 + (((4 + lhi) ^ fb) << 3)];       \
    }                                                                         \
    _Pragma("unroll") for (int mi = 0; mi < 4; ++mi)                          \
      _Pragma("unroll") for (int ni = 0; ni < 2; ++ni)                        \
        accE[mi][ni] = __builtin_amdgcn_mfma_f32_16x16x32_bf16(               \
            fe[mi], fxe[ni], accE[mi][ni], 0, 0, 0);                          \
    _Pragma("unroll") for (int mi = 0; mi < 4; ++mi)                          \
      _Pragma("unroll") for (int ni = 0; ni < 2; ++ni)                        \
        accO[mi][ni] = __builtin_amdgcn_mfma_f32_16x16x32_bf16(               \
            fo[mi], fxo[ni], accO[mi][ni], 0, 0, 0);                          \
  } while (0)

  // ---- prologue: issue step 0's loads; STEP(0) drains them at its top ----
  ISSUE_A(0);
  LOAD_X(0, xrA);

#pragma unroll
  for (int ss = 0; ss < 8; ++ss) {
    STEP(2 * ss,     xrA, xrB);
    STEP(2 * ss + 1, xrB, xrA);
  }

  // ---- epilogue: out[j] = Ye+Yo, out[1023-j] = Ye-Yo ----
  // C/D layout (m89-verified): col = lane&15, row = (lane>>4)*4 + reg
  float* Cb = C + (size_t)b * NN * MM;
  const int jbase = jt * 64 + lhi * 4;
  const int cbase = ct * 32 + llo;
#pragma unroll
  for (int mi = 0; mi < 4; ++mi)
#pragma unroll
    for (int ni = 0; ni < 2; ++ni) {
      const int jh = jbase + mi * 16;
      const int c  = cbase + ni * 16;
#pragma unroll
      for (int r = 0; r < 4; ++r) {
        const float ye = accE[mi][ni][r];
        const float yo = accO[mi][ni][r];
        Cb[(size_t)(jh + r) * MM + c]            = ye + yo;
        Cb[(size_t)(NN - 1 - (jh + r)) * MM + c] = ye - yo;
      }
    }
#undef ISSUE_A
#undef LOAD_X
#undef WRITE_X
#undef STEP
}

extern "C" void kernel_launch(void* const* d_in, const int* in_sizes, int n_in,
                              void* d_out, int out_size, void* d_ws, size_t ws_size,
                              hipStream_t stream) {
  const float* x = (const float*)d_in[0];
  float* out = (float*)d_out;
  u16* G = (u16*)d_ws;  // 524288 u16 = 1 MiB

  fill_g<<<dim3(524288 / 256), dim3(256), 0, stream>>>(G);
  gemm_idct<<<dim3(4096), dim3(64), 0, stream>>>(G, x, out);
}

// Round 12
// 55.264 us; speedup vs baseline: 1.1254x; 1.1254x over previous
//
#include <hip/hip_runtime.h>

typedef unsigned short u16;
typedef __attribute__((ext_vector_type(8))) __bf16 bf16x8;
typedef __attribute__((ext_vector_type(4))) float f32x4;

#define GLOAD_LDS16(g, l)                                                                     \
  __builtin_amdgcn_global_load_lds((const __attribute__((address_space(1))) unsigned int*)(g), \
                                   (__attribute__((address_space(3))) unsigned int*)(l), 16, 0, 0)

static __device__ __forceinline__ u16 f2bf(float f) {
  unsigned int u = __float_as_uint(f);
  u += 0x7fffu + ((u >> 16) & 1u);   // round-to-nearest-even
  return (u16)(u >> 16);
}

// Problem constants
#define BATCH 32
#define NN 1024   // transform length
#define MM 512    // columns
#define KH 512    // folded K (p axis)

// ---- kernel 1: pre-swizzled E|O matrix G[jt(4)][s(16)][row(128)][64 u16] ----
// Row (jt,s,row): physical chunk pc holds data chunk dc = pc ^ (row&7):
//   dc<4 : E, k = 2*(s*32 + dc*8 + sub)        -> M[j][k]
//   dc>=4: O, k = 2*(s*32 + (dc-4)*8 + sub)+1  -> M[j][k],  j = jt*128+row
__global__ void fill_g(u16* __restrict__ G) {
  int idx = blockIdx.x * 256 + threadIdx.x;  // 4*16*128*64 = 524288
  int jt  = idx >> 17;
  int s   = (idx >> 13) & 15;
  int row = (idx >> 6) & 127;
  int pc  = (idx >> 3) & 7;
  int sub = idx & 7;
  int dc = pc ^ (row & 7);
  int j = jt * 128 + row;
  int k;
  if (dc < 4) k = 2 * (s * 32 + dc * 8 + sub);
  else        k = 2 * (s * 32 + (dc - 4) * 8 + sub) + 1;
  float v;
  if (k == 0) {
    v = 0.03125f;  // 1/sqrt(1024)
  } else {
    int ph = (k * (2 * j + 1)) & 4095;
    v = 0.04419417382415922f * cosf((float)ph * 1.5339807878856412e-3f);
  }
  G[idx] = f2bf(v);
}

// ---- kernel 2: transpose/convert/split into step-blocked layout ----
// x[b][k][c] f32 -> xeo[b][c][st(16)][64 u16]: positions 0..31 = E (p = st*32+pl),
// 32..63 = O. LINEAR (swizzle applied by the GEMM's per-lane source address).
__global__ void conv_t(const float* __restrict__ x, u16* __restrict__ xeo) {
  __shared__ u16 tile[32][34];
  const int b = blockIdx.z;
  const int k0 = blockIdx.y << 5;   // by*32
  const int c0 = blockIdx.x << 5;
  const int t = threadIdx.x;
  {
    const int r = t >> 3;
    const int c4 = (t & 7) << 2;
    const float4 v = *(const float4*)(x + ((size_t)b * NN + k0 + r) * MM + c0 + c4);
    tile[c4 + 0][r] = f2bf(v.x);
    tile[c4 + 1][r] = f2bf(v.y);
    tile[c4 + 2][r] = f2bf(v.z);
    tile[c4 + 3][r] = f2bf(v.w);
  }
  __syncthreads();
  {
    const int c = t >> 3;
    const int ko = (t & 7) << 2;          // 0..28 step 4
    const int st = (k0 + ko) >> 6;        // constant per block
    const int pl = ((k0 + ko) >> 1) & 31; // even
    ushort2 e, o;
    e.x = tile[c][ko + 0]; e.y = tile[c][ko + 2];
    o.x = tile[c][ko + 1]; o.y = tile[c][ko + 3];
    const size_t base = ((size_t)(b * MM + c0 + c) * 16 + st) * 64 + pl;
    *(ushort2*)(xeo + base)      = e;
    *(ushort2*)(xeo + base + 32) = o;
  }
}

// ---- kernel 3: folded GEMM, R3 counted-vmcnt phase pipeline, gload_lds-only ----
// Ye=E.Xe, Yo=O.Xo per 128jh x 256c tile; out[j]=Ye+Yo, out[1023-j]=Ye-Yo.
// 512 thr / 8 waves (wm2 x wn4); per wave out 64jh x 64c (x2 E/O). Grid 256 = 1/CU.
// LDS: sA[2][128][64] 32K + sX[2][256][64] 64K = 96 KiB. No ds_writes anywhere.
// Step t (32 p), phases P0 (jh 0..63), P1 (jh 64..127):
//   P0: issue A(t+1) [2 gloads -> sA[nxt], idle since t-1]; read X-frags(8)+A-frags(4);
//       16 MFMA; barrier.   [cur-X fully read -> region free]
//   P1: issue X(t+2) [4 gloads -> sX[cur], freed at P0]; read A-frags(4); 16 MFMA;
//       gate vmcnt(4) [drains A(t+1),X(t+1); X(t+2) rides across]; barrier.
// Frag reads always drain before their MFMAs (compiler lgkm) hence before barriers,
// so cross-wave LDS overwrite is always >=1 barrier after last read.  Gates:
// t<14: vmcnt(4); t==14: vmcnt(0); t==15: none.  Regs: 128 acc + ~110 VGPR <= 256.
__global__ __launch_bounds__(512, 2) void gemm_idct(const u16* __restrict__ G,
                                                    const u16* __restrict__ Xeo,
                                                    float* __restrict__ C) {
  __shared__ __align__(16) u16 sA[2][8192];   // [buf][128 row][64]
  __shared__ __align__(16) u16 sX[2][16384];  // [buf][256 row][64]
  // --- XCD decode: 4 jt-sharers of each (ct,b) X-panel on one XCD ---
  const int wg    = blockIdx.x;
  const int xcd   = wg & 7;
  const int local = wg >> 3;              // 0..31
  const int jt    = local & 3;            // jh tile 0..3 (128 rows)
  const int panel = xcd * 8 + (local >> 2);  // 0..63
  const int ct    = panel & 1;            // c tile 0..1 (256 cols)
  const int b     = panel >> 1;           // batch

  const int t512 = threadIdx.x;
  const int wave = t512 >> 6, lane = t512 & 63;
  const int wm = wave >> 2, wn = wave & 3;
  const int lhi = lane >> 4, llo = lane & 15;

  // --- staging sources ---
  const int tr = t512 >> 3;                    // row-in-64-group
  const u16* gA = G + (size_t)jt * 131072 + (size_t)tr * 64 + (t512 & 7) * 8;  // pre-swizzled
  const int dcx = (t512 & 7) ^ (tr & 7);       // per-lane swizzle for X
  const u16* gX = Xeo + (((size_t)(b * MM + ct * 256 + tr)) * 16) * 64 + dcx * 8;

#define ISSUE_A(buf, tt)                                                      \
  do {                                                                        \
    _Pragma("unroll") for (int h = 0; h < 2; ++h)                             \
      GLOAD_LDS16(gA + (tt) * 8192 + h * 4096, &sA[buf][h * 4096 + t512 * 8]); \
  } while (0)
#define ISSUE_X(buf, tt)                                                      \
  do {                                                                        \
    _Pragma("unroll") for (int v = 0; v < 4; ++v)                             \
      GLOAD_LDS16(gX + (size_t)v * 65536 + (tt) * 64, &sX[buf][v * 4096 + t512 * 8]); \
  } while (0)

#define SBAR()                              \
  do {                                      \
    __builtin_amdgcn_sched_barrier(0);      \
    __builtin_amdgcn_s_barrier();           \
    __builtin_amdgcn_sched_barrier(0);      \
  } while (0)

  f32x4 accE[4][4] = {};
  f32x4 accO[4][4] = {};

  // ---- prologue: X(0),A(0),X(1); drain tile0 (6 oldest), keep X(1) in flight ----
  ISSUE_X(0, 0);
  ISSUE_A(0, 0);
  ISSUE_X(1, 1);
  asm volatile("s_waitcnt vmcnt(4)" ::: "memory");
  SBAR();

  for (int t = 0; t < 16; ++t) {
    const int cur = t & 1, nxt = cur ^ 1;
    const u16* lA = &sA[cur][0];
    const u16* lX = &sX[cur][0];
    bf16x8 fxe[4], fxo[4];

    // ---- P0: jh rows 0..63 ----
    if (t < 15) ISSUE_A(nxt, t + 1);
#pragma unroll
    for (int nf = 0; nf < 4; ++nf) {
      const int row = wn * 64 + nf * 16 + llo;
      const int f = row & 7;
      fxe[nf] = *(const bf16x8*)&lX[row * 64 + ((lhi ^ f) << 3)];
      fxo[nf] = *(const bf16x8*)&lX[row * 64 + (((4 + lhi) ^ f) << 3)];
    }
    {
      bf16x8 fe[2], fo[2];
#pragma unroll
      for (int mf = 0; mf < 2; ++mf) {
        const int row = wm * 32 + mf * 16 + llo;
        const int f = row & 7;
        fe[mf] = *(const bf16x8*)&lA[row * 64 + ((lhi ^ f) << 3)];
        fo[mf] = *(const bf16x8*)&lA[row * 64 + (((4 + lhi) ^ f) << 3)];
      }
      __builtin_amdgcn_s_setprio(1);
#pragma unroll
      for (int mf = 0; mf < 2; ++mf)
#pragma unroll
        for (int nf = 0; nf < 4; ++nf)
          accE[mf][nf] = __builtin_amdgcn_mfma_f32_16x16x32_bf16(
              fe[mf], fxe[nf], accE[mf][nf], 0, 0, 0);
#pragma unroll
      for (int mf = 0; mf < 2; ++mf)
#pragma unroll
        for (int nf = 0; nf < 4; ++nf)
          accO[mf][nf] = __builtin_amdgcn_mfma_f32_16x16x32_bf16(
              fo[mf], fxo[nf], accO[mf][nf], 0, 0, 0);
      __builtin_amdgcn_s_setprio(0);
    }
    SBAR();

    // ---- P1: jh rows 64..127 ----
    if (t < 14) ISSUE_X(cur, t + 2);
    {
      bf16x8 fe[2], fo[2];
#pragma unroll
      for (int mf = 0; mf < 2; ++mf) {
        const int row = 64 + wm * 32 + mf * 16 + llo;
        const int f = row & 7;
        fe[mf] = *(const bf16x8*)&lA[row * 64 + ((lhi ^ f) << 3)];
        fo[mf] = *(const bf16x8*)&lA[row * 64 + (((4 + lhi) ^ f) << 3)];
      }
      __builtin_amdgcn_s_setprio(1);
#pragma unroll
      for (int mf = 0; mf < 2; ++mf)
#pragma unroll
        for (int nf = 0; nf < 4; ++nf)
          accE[2 + mf][nf] = __builtin_amdgcn_mfma_f32_16x16x32_bf16(
              fe[mf], fxe[nf], accE[2 + mf][nf], 0, 0, 0);
#pragma unroll
      for (int mf = 0; mf < 2; ++mf)
#pragma unroll
        for (int nf = 0; nf < 4; ++nf)
          accO[2 + mf][nf] = __builtin_amdgcn_mfma_f32_16x16x32_bf16(
              fo[mf], fxo[nf], accO[2 + mf][nf], 0, 0, 0);
      __builtin_amdgcn_s_setprio(0);
    }
    if (t < 14)
      asm volatile("s_waitcnt vmcnt(4)" ::: "memory");
    else if (t == 14)
      asm volatile("s_waitcnt vmcnt(0)" ::: "memory");
    SBAR();
  }

  // ---- epilogue: out[j] = Ye+Yo, out[1023-j] = Ye-Yo ----
  // C/D layout (m89-verified): col = lane&15, row = (lane>>4)*4 + reg
  float* Cb = C + (size_t)b * NN * MM;
  const int cbase = ct * 256 + wn * 64 + llo;
#pragma unroll
  for (int qm = 0; qm < 4; ++qm) {  // qm = q*2 + mf: jh = q*64 + wm*32 + mf*16
    const int q = qm >> 1, mf = qm & 1;
    const int jh0 = jt * 128 + q * 64 + wm * 32 + mf * 16 + lhi * 4;
#pragma unroll
    for (int nf = 0; nf < 4; ++nf) {
      const int c = cbase + nf * 16;
#pragma unroll
      for (int r = 0; r < 4; ++r) {
        const float ye = accE[qm][nf][r];
        const float yo = accO[qm][nf][r];
        const int j = jh0 + r;
        Cb[(size_t)j * MM + c]            = ye + yo;
        Cb[(size_t)(NN - 1 - j) * MM + c] = ye - yo;
      }
    }
  }
#undef ISSUE_A
#undef ISSUE_X
#undef SBAR
}

extern "C" void kernel_launch(void* const* d_in, const int* in_sizes, int n_in,
                              void* d_out, int out_size, void* d_ws, size_t ws_size,
                              hipStream_t stream) {
  const float* x = (const float*)d_in[0];
  float* out = (float*)d_out;
  u16* G   = (u16*)d_ws;                       // 1 MiB
  u16* xeo = G + (size_t)524288;               // 32 MiB

  fill_g<<<dim3(2048), dim3(256), 0, stream>>>(G);
  conv_t<<<dim3(MM / 32, NN / 32, BATCH), dim3(256), 0, stream>>>(x, xeo);
  gemm_idct<<<dim3(256), dim3(512), 0, stream>>>(G, xeo, out);
}

// Round 14
// 49.038 us; speedup vs baseline: 1.2683x; 1.1270x over previous
//
#include <hip/hip_runtime.h>

typedef unsigned short u16;
typedef __attribute__((ext_vector_type(8))) __bf16 bf16x8;
typedef __attribute__((ext_vector_type(4))) float f32x4;

#define GLOAD_LDS16(g, l)                                                                     \
  __builtin_amdgcn_global_load_lds((const __attribute__((address_space(1))) unsigned int*)(g), \
                                   (__attribute__((address_space(3))) unsigned int*)(l), 16, 0, 0)

static __device__ __forceinline__ u16 f2bf(float f) {
  unsigned int u = __float_as_uint(f);
  u += 0x7fffu + ((u >> 16) & 1u);   // round-to-nearest-even
  return (u16)(u >> 16);
}

// Problem constants
#define BATCH 32
#define NN 1024
#define MM 512

// sX swizzle (R10-proven, 0 conflicts): 2-way max on row-step-1 reads and
// row-step-2 transpose writes (2-way = free, m136).
static __device__ __forceinline__ int swz(int r) { return ((r >> 1) ^ ((r & 1) << 2)) & 7; }

// ---- kernel 1 (R12-verbatim): pre-swizzled E|O matrix G[jt(4)][s(16)][row(128)][64] ----
// Row (jt,s,row): physical chunk pc holds data chunk dc = pc ^ (row&7):
//   dc<4 : E, k = 2*(s*32 + dc*8 + sub);  dc>=4: O, k = 2*(s*32+(dc-4)*8+sub)+1
__global__ void fill_g(u16* __restrict__ G) {
  int idx = blockIdx.x * 256 + threadIdx.x;  // 4*16*128*64 = 524288
  int jt  = idx >> 17;
  int s   = (idx >> 13) & 15;
  int row = (idx >> 6) & 127;
  int pc  = (idx >> 3) & 7;
  int sub = idx & 7;
  int dc = pc ^ (row & 7);
  int j = jt * 128 + row;
  int k;
  if (dc < 4) k = 2 * (s * 32 + dc * 8 + sub);
  else        k = 2 * (s * 32 + (dc - 4) * 8 + sub) + 1;
  float v;
  if (k == 0) {
    v = 0.03125f;  // 1/sqrt(1024)
  } else {
    int ph = (k * (2 * j + 1)) & 4095;
    v = 0.04419417382415922f * cosf((float)ph * 1.5339807878856412e-3f);
  }
  G[idx] = f2bf(v);
}

// ---- kernel 2: fused folded GEMM, depth-2 X pipeline, counted gates ----
// out[j] = (E.Xe + O.Xo)[j], out[1023-j] = (E.Xe - O.Xo)[j].
// Block 256 thr / 4 waves (2wm x 2wn), tile 128jh x 64c; wave 64jh x 32c (E+O).
// LDS: sA[2][128*64] 32K (G via linear gload_lds, dbuf) + sX[64*64] 8K = 40K.
// Step s: WRITE_X(s) [auto reg-wait drains thru X(s)]; vmcnt(8)+lgkm(0) [drains
// A(s), X(s+1) rides]; b1; ISSUE_A(s+1)->sA[(s+1)&1]; LOAD_X(s+2)->set freed now;
// 12 frag reads; 16 MFMA; b2 (bare).
// X consumed ~1.5 steps after issue (>HBM lat). Gates: s<15: vmcnt(8); s==15: 0.
// R13 bug fixed: A-buffer index was (s)^1&1 = s^1 (OOB for s>=2); now ((s)+1)&1.
__global__ __launch_bounds__(256, 2) void gemm_idct(const u16* __restrict__ G,
                                                    const float* __restrict__ X,
                                                    float* __restrict__ C) {
  __shared__ __align__(16) u16 sA[2][8192];  // [buf][128 row][64]
  __shared__ __align__(16) u16 sX[4096];     // [64 c-row][64] (32 E | 32 O)
  // --- XCD decode: 4 jt-sharers of each (ct,b) X-panel share wg&7 ---
  const int wg    = blockIdx.x;
  const int xcd   = wg & 7;
  const int local = wg >> 3;                  // 0..127
  const int jt    = local & 3;                // jh tile (128 rows)
  const int pg    = xcd * 32 + (local >> 2);  // 0..255
  const int ct    = pg & 7;                   // c tile (64 cols)
  const int b     = pg >> 3;                  // batch

  const int t = threadIdx.x;
  const int wave = t >> 6, lane = t & 63;
  const int wm = wave >> 1, wn = wave & 1;
  const int lhi = lane >> 4, llo = lane & 15;

  // --- A staging: 4 calls x 4KB; source linear (pre-swizzled at fill) ---
  const u16* gA = G + (size_t)jt * 131072 + t * 8;
#define ISSUE_A(buf, s)                                                        \
  do {                                                                         \
    _Pragma("unroll") for (int cl = 0; cl < 4; ++cl)                           \
      GLOAD_LDS16(gA + (s) * 8192 + cl * 2048, &sA[buf][cl * 2048 + t * 8]);   \
  } while (0)

  // --- X: lane owns c-pair {2*(t&31), +1}, k-eighth kq = t>>5 (8 k per step) ---
  const int c2 = (t & 31) << 1;
  const int kq = t >> 5;
  const float* gX = X + ((size_t)b * NN + kq * 8) * MM + ct * 64 + c2;

#define LOAD_X(s, XR)                                                          \
  do {                                                                         \
    const float* p = gX + (size_t)(s) * 64 * MM;                               \
    _Pragma("unroll") for (int i = 0; i < 8; ++i)                              \
      XR[i] = *(const float2*)(p + (size_t)i * MM);                            \
  } while (0)

  // E: k=kq*8+2j -> p-local = kq*4+j = chunk (kq>>1), slot (kq&1)*4+j; O: +4 chunks.
#define WRITE_X(XR)                                                            \
  do {                                                                         \
    _Pragma("unroll") for (int cc = 0; cc < 2; ++cc) {                         \
      const int row = c2 + cc;                                                 \
      const int f = swz(row);                                                  \
      ushort4 e, o;                                                            \
      e.x = f2bf(cc ? XR[0].y : XR[0].x); o.x = f2bf(cc ? XR[1].y : XR[1].x);  \
      e.y = f2bf(cc ? XR[2].y : XR[2].x); o.y = f2bf(cc ? XR[3].y : XR[3].x);  \
      e.z = f2bf(cc ? XR[4].y : XR[4].x); o.z = f2bf(cc ? XR[5].y : XR[5].x);  \
      e.w = f2bf(cc ? XR[6].y : XR[6].x); o.w = f2bf(cc ? XR[7].y : XR[7].x);  \
      const int slot = (kq & 1) << 2;                                          \
      *(ushort4*)&sX[row * 64 + (((kq >> 1) ^ f) << 3) + slot] = e;            \
      *(ushort4*)&sX[row * 64 + (((4 + (kq >> 1)) ^ f) << 3) + slot] = o;      \
    }                                                                          \
  } while (0)

  f32x4 accE[4][2] = {};
  f32x4 accO[4][2] = {};
  float2 xrA[8], xrB[8];

#define STEP(s, XR)                                                            \
  do {                                                                         \
    WRITE_X(XR); /* compiler waits XR regs; drains everything older */         \
    if ((s) < 15)                                                              \
      asm volatile("s_waitcnt vmcnt(8) lgkmcnt(0)" ::: "memory");              \
    else                                                                       \
      asm volatile("s_waitcnt vmcnt(0) lgkmcnt(0)" ::: "memory");              \
    __builtin_amdgcn_sched_barrier(0);                                         \
    __builtin_amdgcn_s_barrier(); /* b1: sA[s&1]+sX ready everywhere */        \
    __builtin_amdgcn_sched_barrier(0);                                         \
    if ((s) < 15) ISSUE_A(((s) + 1) & 1, (s) + 1);                             \
    if ((s) < 14) LOAD_X((s) + 2, XR);                                         \
    {                                                                          \
      const u16* lA = &sA[(s) & 1][0];                                         \
      bf16x8 fe[4], fo[4], fxe[2], fxo[2];                                     \
      _Pragma("unroll") for (int mf = 0; mf < 4; ++mf) {                       \
        const int ra = wm * 64 + mf * 16 + llo;                                \
        const int fa = ra & 7;                                                 \
        fe[mf] = *(const bf16x8*)&lA[ra * 64 + ((lhi ^ fa) << 3)];             \
        fo[mf] = *(const bf16x8*)&lA[ra * 64 + (((4 + lhi) ^ fa) << 3)];       \
      }                                                                        \
      _Pragma("unroll") for (int nf = 0; nf < 2; ++nf) {                       \
        const int rb = wn * 32 + nf * 16 + llo;                                \
        const int fb = swz(rb);                                                \
        fxe[nf] = *(const bf16x8*)&sX[rb * 64 + ((lhi ^ fb) << 3)];            \
        fxo[nf] = *(const bf16x8*)&sX[rb * 64 + (((4 + lhi) ^ fb) << 3)];      \
      }                                                                        \
      __builtin_amdgcn_s_setprio(1);                                           \
      _Pragma("unroll") for (int mf = 0; mf < 4; ++mf)                         \
        _Pragma("unroll") for (int nf = 0; nf < 2; ++nf)                       \
          accE[mf][nf] = __builtin_amdgcn_mfma_f32_16x16x32_bf16(              \
              fe[mf], fxe[nf], accE[mf][nf], 0, 0, 0);                         \
      _Pragma("unroll") for (int mf = 0; mf < 4; ++mf)                         \
        _Pragma("unroll") for (int nf = 0; nf < 2; ++nf)                       \
          accO[mf][nf] = __builtin_amdgcn_mfma_f32_16x16x32_bf16(              \
              fo[mf], fxo[nf], accO[mf][nf], 0, 0, 0);                         \
      __builtin_amdgcn_s_setprio(0);                                           \
    }                                                                          \
    __builtin_amdgcn_sched_barrier(0);                                         \
    __builtin_amdgcn_s_barrier(); /* b2: bare */                               \
    __builtin_amdgcn_sched_barrier(0);                                         \
  } while (0)

  // ---- prologue: X(0)->A, A(0), X(1)->B; STEP(0) drains at its gate ----
  LOAD_X(0, xrA);
  ISSUE_A(0, 0);
  LOAD_X(1, xrB);

#pragma unroll
  for (int ss = 0; ss < 8; ++ss) {
    STEP(2 * ss,     xrA);
    STEP(2 * ss + 1, xrB);
  }

  // ---- epilogue: out[j] = Ye+Yo, out[1023-j] = Ye-Yo ----
  // C/D layout (m89-verified): col = lane&15, row = (lane>>4)*4 + reg
  float* Cb = C + (size_t)b * NN * MM;
  const int cbase = ct * 64 + wn * 32 + llo;
#pragma unroll
  for (int mf = 0; mf < 4; ++mf)
#pragma unroll
    for (int nf = 0; nf < 2; ++nf) {
      const int jh0 = jt * 128 + wm * 64 + mf * 16 + lhi * 4;
      const int c   = cbase + nf * 16;
#pragma unroll
      for (int r = 0; r < 4; ++r) {
        const float ye = accE[mf][nf][r];
        const float yo = accO[mf][nf][r];
        const int j = jh0 + r;
        Cb[(size_t)j * MM + c]            = ye + yo;
        Cb[(size_t)(NN - 1 - j) * MM + c] = ye - yo;
      }
    }
#undef ISSUE_A
#undef LOAD_X
#undef WRITE_X
#undef STEP
}

extern "C" void kernel_launch(void* const* d_in, const int* in_sizes, int n_in,
                              void* d_out, int out_size, void* d_ws, size_t ws_size,
                              hipStream_t stream) {
  const float* x = (const float*)d_in[0];
  float* out = (float*)d_out;
  u16* G = (u16*)d_ws;  // 524288 u16 = 1 MiB

  fill_g<<<dim3(2048), dim3(256), 0, stream>>>(G);
  gemm_idct<<<dim3(1024), dim3(256), 0, stream>>>(G, x, out);
}